// Round 8
// baseline (30.882 us; speedup 1.0000x reference)
//
#include <hip/hip_runtime.h>
#include <math.h>

// DynamicTrackHead — R8: R7 structure, K1 at waves_per_eu=6 (85-VGPR budget).
// Theory: occupancy = floor(512/VGPR) continuously, not pow2 buckets; 85-VGPR
// budget -> 6 waves/SIMD = 24 waves/CU (vs 16 at R7's 128-budget) with no
// spill (structure needs ~55-75). Single-lever A/B vs R7.
// K1: grid (n_inst, 2, 30), block 64 = one wave. 2 threads per pooled pixel
//     (tid>>5 = qy half), 32 pixels/block. conv0+conv1 in regs; qy-pool via
//     __shfl_xor(32); m1 staged to 1 KB LDS; conv2 one channel/thread
//     (broadcast LDS reads); 64 partials to d_ws.
// K2: grid (n_inst, 2), block 128. Sum 30 partials -> mean -> MLP -> out.
// params/instance = 736 floats: w0[8][10]@0, w1[8][8]@80, w2[64][8]@144,
// b0@656, b1@664, b2@672.

#define H_IN 96
#define W_IN 160
#define HW_IN (H_IN * W_IN)
#define PW 40            // W_IN / 4
#define PH 24            // H_IN / 4
#define NPIX (PH * PW)   // 960 pooled-twice pixels
#define NCHUNK 30        // K1 blocks per (inst,head)
#define CPIX 32          // pooled pixels per K1 block
#define NPARAM 736
#define OW0 0
#define OW1 80
#define OW2 144
#define OB0 656
#define OB1 664
#define OB2 672

#define SELU_SCALE 1.0507009873554805f
#define SELU_ALPHA 1.6732632423543772f

// ---------------------------------------------------------------------------
// K1: conv tower + partial spatial sum. One wave per block.
// ---------------------------------------------------------------------------
__global__ __launch_bounds__(64, 6) void track_head_conv(
    const float* __restrict__ mask_feats,
    const float* __restrict__ pmain,
    const float* __restrict__ pside,
    const int*   __restrict__ im_inds,
    const float* __restrict__ inst_loc,
    const float* __restrict__ offset_pred,
    const int*   __restrict__ fpn_levels,
    const int*   __restrict__ stride_ptr,
    float*       __restrict__ ws_part)      // [n_inst][2][NCHUNK][64]
{
    const int inst  = blockIdx.x;
    const int head  = blockIdx.y;
    const int chunk = blockIdx.z;
    const int tid   = threadIdx.x;          // 0..63
    const int pix   = tid & 31;             // pixel within chunk
    const int qy    = tid >> 5;             // which pool-2 row half

    __shared__ __align__(16) float s_m1[CPIX][8];   // 1 KB

    const float* __restrict__ P = (head ? pside : pmain) + (size_t)inst * NPARAM;

    const int S  = stride_ptr[0];
    const int S2 = S / 2;
    float lx = inst_loc[inst * 2 + 0];
    float ly = inst_loc[inst * 2 + 1];
    if (head) {
        lx += offset_pred[inst * 2 + 0] * 128.0f;
        ly += offset_pred[inst * 2 + 1] * 128.0f;
    }
    const float inv_soi = 1.0f / (float)(64 << fpn_levels[inst]);
    const float* __restrict__ feat =
        mask_feats + (size_t)im_inds[inst] * 8 * HW_IN;

    const int p   = chunk * CPIX + pix;     // 0..959
    const int py  = p / PW;
    const int px  = p - py * PW;
    const int ix0 = px * 4;
    const int iyb = py * 4 + qy * 2;        // this thread's two input rows

    // ---- conv0 (relu folded into max), accumulate quadrant maxes ----
    float m0a[8], m0b[8];                   // pool-1 pixels (qy,qx=0/1), >=0
    #pragma unroll
    for (int o = 0; o < 8; o++) { m0a[o] = 0.0f; m0b[o] = 0.0f; }

    #pragma unroll
    for (int sy = 0; sy < 2; sy++) {
        const int iy = iyb + sy;
        const float x1 = (ly - (float)(iy * S + S2)) * inv_soi;
        const float* rowp = feat + iy * W_IN + ix0;
        const float4 f0 = *(const float4*)(rowp + 0 * HW_IN);
        const float4 f1 = *(const float4*)(rowp + 1 * HW_IN);
        const float4 f2 = *(const float4*)(rowp + 2 * HW_IN);
        const float4 f3 = *(const float4*)(rowp + 3 * HW_IN);
        const float4 f4 = *(const float4*)(rowp + 4 * HW_IN);
        const float4 f5 = *(const float4*)(rowp + 5 * HW_IN);
        const float4 f6 = *(const float4*)(rowp + 6 * HW_IN);
        const float4 f7 = *(const float4*)(rowp + 7 * HW_IN);

#define L0_PIX(JJ, COMP, M0ARR)                                                 \
        {                                                                       \
            const float x0 = (lx - (float)((ix0 + JJ) * S + S2)) * inv_soi;     \
            _Pragma("unroll")                                                   \
            for (int o = 0; o < 8; o++) {                                       \
                const float* w0r = P + OW0 + o * 10;                            \
                float a = P[OB0 + o] + w0r[0] * x0 + w0r[1] * x1                \
                        + w0r[2] * f0.COMP + w0r[3] * f1.COMP                   \
                        + w0r[4] * f2.COMP + w0r[5] * f3.COMP                   \
                        + w0r[6] * f4.COMP + w0r[7] * f5.COMP                   \
                        + w0r[8] * f6.COMP + w0r[9] * f7.COMP;                  \
                M0ARR[o] = fmaxf(M0ARR[o], a);                                  \
            }                                                                   \
        }
        L0_PIX(0, x, m0a)
        L0_PIX(1, y, m0a)
        L0_PIX(2, z, m0b)
        L0_PIX(3, w, m0b)
#undef L0_PIX
    }

    // ---- conv1 (relu) + pool over qx (local) and qy (cross-lane) ----
    float m1[8];
    #pragma unroll
    for (int o = 0; o < 8; o++) {
        float a = P[OB1 + o];
        float b = a;
        #pragma unroll
        for (int c = 0; c < 8; c++) {
            const float w = P[OW1 + o * 8 + c];
            a += w * m0a[c];
            b += w * m0b[c];
        }
        const float h = fmaxf(fmaxf(a, b), 0.0f);
        m1[o] = fmaxf(h, __shfl_xor(h, 32, 64));   // pool across qy halves
    }

    // ---- stage m1 to LDS (both halves hold identical values; benign) ----
    {
        float4* dst = (float4*)&s_m1[pix][0];
        dst[0] = make_float4(m1[0], m1[1], m1[2], m1[3]);
        dst[1] = make_float4(m1[4], m1[5], m1[6], m1[7]);
    }
    __syncthreads();

    // ---- conv2 (relu): one output channel per thread, broadcast LDS reads --
    {
        const int o = tid;                    // output channel 0..63
        const float4 wa = *(const float4*)(P + OW2 + o * 8);
        const float4 wb = *(const float4*)(P + OW2 + o * 8 + 4);
        const float  bo = P[OB2 + o];
        float accum = 0.0f;
        #pragma unroll 4
        for (int p2 = 0; p2 < CPIX; p2++) {
            const float4 va = *(const float4*)&s_m1[p2][0];   // broadcast read
            const float4 vb = *(const float4*)&s_m1[p2][4];
            float a = bo + wa.x * va.x + wa.y * va.y + wa.z * va.z + wa.w * va.w
                         + wb.x * vb.x + wb.y * vb.y + wb.z * vb.z + wb.w * vb.w;
            accum += fmaxf(a, 0.0f);
        }
        ws_part[(((size_t)inst * 2 + head) * NCHUNK + chunk) * 64 + o] = accum;
    }
}

// ---------------------------------------------------------------------------
// K2: combine partials -> mean -> MLP (fc1 -> LN -> SELU -> fc2) -> logits
// ---------------------------------------------------------------------------
__global__ __launch_bounds__(128) void track_head_mlp(
    const float* __restrict__ ws_part,
    const float* __restrict__ mw1, const float* __restrict__ mb1,
    const float* __restrict__ mg,  const float* __restrict__ mbeta,
    const float* __restrict__ mw2, const float* __restrict__ mb2,
    const float* __restrict__ sw1, const float* __restrict__ sb1,
    const float* __restrict__ sg,  const float* __restrict__ sbeta,
    const float* __restrict__ sw2, const float* __restrict__ sb2,
    float*       __restrict__ out,
    int n_inst)
{
    const int inst = blockIdx.x;
    const int head = blockIdx.y;
    const int tid  = threadIdx.x;
    const int lane = tid & 63;
    const int wid  = tid >> 6;

    __shared__ __align__(16) float s_x[64];
    __shared__ __align__(16) float s_h[128];
    __shared__ float s_r[4];

    if (tid < 64) {
        const float* base = ws_part + ((size_t)inst * 2 + head) * NCHUNK * 64 + tid;
        float xm = 0.0f;
        #pragma unroll
        for (int q = 0; q < NCHUNK; q++) xm += base[q * 64];
        s_x[tid] = xm * (1.0f / (float)NPIX);
    }
    __syncthreads();

    const float* __restrict__ w1h = head ? sw1 : mw1;
    const float* __restrict__ b1h = head ? sb1 : mb1;
    const float* __restrict__ gh  = head ? sg  : mg;
    const float* __restrict__ bth = head ? sbeta : mbeta;
    const float* __restrict__ w2h = head ? sw2 : mw2;
    const float* __restrict__ b2h = head ? sb2 : mb2;

    float hval = 0.0f, dval = 0.0f;
    {
        const float* wr = w1h + tid * 64;
        float a = b1h[tid];
        #pragma unroll
        for (int k = 0; k < 16; k++) {
            const float4 wv = *(const float4*)(wr + k * 4);
            const float4 xv = *(const float4*)(&s_x[k * 4]);
            a += wv.x * xv.x + wv.y * xv.y + wv.z * xv.z + wv.w * xv.w;
        }
        hval = a;
    }
    {
        float s = hval;
        #pragma unroll
        for (int m = 32; m >= 1; m >>= 1) s += __shfl_xor(s, m, 64);
        if (lane == 0) s_r[wid] = s;
    }
    __syncthreads();
    const float mu = (s_r[0] + s_r[1]) * (1.0f / 128.0f);
    dval = hval - mu;
    {
        float s = dval * dval;
        #pragma unroll
        for (int m = 32; m >= 1; m >>= 1) s += __shfl_xor(s, m, 64);
        if (lane == 0) s_r[wid + 2] = s;
    }
    __syncthreads();
    const float var = (s_r[2] + s_r[3]) * (1.0f / 128.0f);

    {
        const float hn = dval * (1.0f / sqrtf(var + 1e-5f)) * gh[tid] + bth[tid];
        const float sv = (hn > 0.0f)
                           ? SELU_SCALE * hn
                           : SELU_SCALE * SELU_ALPHA * (expf(hn) - 1.0f);
        s_h[tid] = sv;
    }
    __syncthreads();

    if (tid < 64) {
        const float* wr = w2h + tid * 128;
        float a = b2h[tid];
        #pragma unroll
        for (int k = 0; k < 32; k++) {
            const float4 wv = *(const float4*)(wr + k * 4);
            const float4 hv = *(const float4*)(&s_h[k * 4]);
            a += wv.x * hv.x + wv.y * hv.y + wv.z * hv.z + wv.w * hv.w;
        }
        out[(size_t)head * (size_t)n_inst * 64 + (size_t)inst * 64 + tid] = a;
    }
}

extern "C" void kernel_launch(void* const* d_in, const int* in_sizes, int n_in,
                              void* d_out, int out_size, void* d_ws, size_t ws_size,
                              hipStream_t stream) {
    const float* mask_feats  = (const float*)d_in[0];
    const float* pmain       = (const float*)d_in[1];
    const float* pside       = (const float*)d_in[2];
    const int*   im_inds     = (const int*)  d_in[3];
    const float* inst_loc    = (const float*)d_in[4];
    const float* offset_pred = (const float*)d_in[5];
    const int*   fpn_levels  = (const int*)  d_in[6];
    const float* mw1   = (const float*)d_in[7];
    const float* mb1   = (const float*)d_in[8];
    const float* mg    = (const float*)d_in[9];
    const float* mbeta = (const float*)d_in[10];
    const float* mw2   = (const float*)d_in[11];
    const float* mb2   = (const float*)d_in[12];
    const float* sw1   = (const float*)d_in[13];
    const float* sb1   = (const float*)d_in[14];
    const float* sg    = (const float*)d_in[15];
    const float* sbeta = (const float*)d_in[16];
    const float* sw2   = (const float*)d_in[17];
    const float* sb2   = (const float*)d_in[18];
    const int*   strid = (const int*)  d_in[19];
    float* out = (float*)d_out;

    const int n_inst = in_sizes[3];   // im_inds length
    float* ws_part = (float*)d_ws;    // n_inst*2*NCHUNK*64 floats ~= 2 MB

    dim3 g1(n_inst, 2, NCHUNK);
    track_head_conv<<<g1, 64, 0, stream>>>(
        mask_feats, pmain, pside, im_inds, inst_loc, offset_pred, fpn_levels,
        strid, ws_part);

    dim3 g2(n_inst, 2);
    track_head_mlp<<<g2, 128, 0, stream>>>(
        ws_part,
        mw1, mb1, mg, mbeta, mw2, mb2,
        sw1, sb1, sg, sbeta, sw2, sb2,
        out, n_inst);
}

// Round 9
// 27.713 us; speedup vs baseline: 1.1144x; 1.1144x over previous
//
#include <hip/hip_runtime.h>
#include <math.h>

// DynamicTrackHead — R9: both heads fused per block (shared feature tile).
// K1: grid (n_inst, NCHUNK=30), block 64 = one wave. 2 threads per pooled
//     pixel (tid>>5 = qy half), 32 pixels/block, BOTH heads per block:
//     feature tile loaded once, conv0/conv1 run per head; qy-pool via
//     __shfl_xor(32); m1 staged to 2 KB LDS; conv2 one channel/thread per
//     head; 2x64 partials to d_ws. Row-base (b0+w1*x1) hoisted per (o,sy,head).
//     3840 blocks = 15/CU -> single occupancy batch at 4 waves/SIMD.
// K2: grid (n_inst, 2), block 128. Sum 30 partials -> mean -> MLP -> out.
// params/instance = 736 floats: w0[8][10]@0, w1[8][8]@80, w2[64][8]@144,
// b0@656, b1@664, b2@672.

#define H_IN 96
#define W_IN 160
#define HW_IN (H_IN * W_IN)
#define PW 40            // W_IN / 4
#define PH 24            // H_IN / 4
#define NPIX (PH * PW)   // 960 pooled-twice pixels
#define NCHUNK 30        // K1 blocks per instance
#define CPIX 32          // pooled pixels per K1 block
#define NPARAM 736
#define OW0 0
#define OW1 80
#define OW2 144
#define OB0 656
#define OB1 664
#define OB2 672

#define SELU_SCALE 1.0507009873554805f
#define SELU_ALPHA 1.6732632423543772f

// ---------------------------------------------------------------------------
// K1: conv tower for BOTH heads + partial spatial sums. One wave per block.
// ---------------------------------------------------------------------------
__global__ __launch_bounds__(64, 4) void track_head_conv(
    const float* __restrict__ mask_feats,
    const float* __restrict__ pmain,
    const float* __restrict__ pside,
    const int*   __restrict__ im_inds,
    const float* __restrict__ inst_loc,
    const float* __restrict__ offset_pred,
    const int*   __restrict__ fpn_levels,
    const int*   __restrict__ stride_ptr,
    float*       __restrict__ ws_part)      // [n_inst][2][NCHUNK][64]
{
    const int inst  = blockIdx.x;
    const int chunk = blockIdx.y;
    const int tid   = threadIdx.x;          // 0..63
    const int pix   = tid & 31;             // pixel within chunk
    const int qy    = tid >> 5;             // which pool-2 row half

    __shared__ __align__(16) float s_m1[2][CPIX][8];   // 2 KB (per head)

    const float* __restrict__ PA = pmain + (size_t)inst * NPARAM;
    const float* __restrict__ PB = pside + (size_t)inst * NPARAM;

    const int S  = stride_ptr[0];
    const int S2 = S / 2;
    const float lxA = inst_loc[inst * 2 + 0];
    const float lyA = inst_loc[inst * 2 + 1];
    const float lxB = lxA + offset_pred[inst * 2 + 0] * 128.0f;
    const float lyB = lyA + offset_pred[inst * 2 + 1] * 128.0f;
    const float inv_soi = 1.0f / (float)(64 << fpn_levels[inst]);
    const float* __restrict__ feat =
        mask_feats + (size_t)im_inds[inst] * 8 * HW_IN;

    const int p   = chunk * CPIX + pix;     // 0..959
    const int py  = p / PW;
    const int px  = p - py * PW;
    const int ix0 = px * 4;
    const int iyb = py * 4 + qy * 2;        // this thread's two input rows

    // x-coordinate channel values for the 4 columns, per head
    float x0A[4], x0B[4];
    #pragma unroll
    for (int j = 0; j < 4; j++) {
        const float xc = (float)((ix0 + j) * S + S2);
        x0A[j] = (lxA - xc) * inv_soi;
        x0B[j] = (lxB - xc) * inv_soi;
    }

    // ---- conv0 (relu folded into max): both heads off one feature tile ----
    float m0aA[8], m0bA[8], m0aB[8], m0bB[8];   // quadrant maxes, >= 0
    #pragma unroll
    for (int o = 0; o < 8; o++) {
        m0aA[o] = 0.0f; m0bA[o] = 0.0f;
        m0aB[o] = 0.0f; m0bB[o] = 0.0f;
    }

    #pragma unroll
    for (int sy = 0; sy < 2; sy++) {
        const int iy = iyb + sy;
        const float yc = (float)(iy * S + S2);
        const float x1A = (lyA - yc) * inv_soi;
        const float x1B = (lyB - yc) * inv_soi;
        const float* rowp = feat + iy * W_IN + ix0;
        const float4 f0 = *(const float4*)(rowp + 0 * HW_IN);
        const float4 f1 = *(const float4*)(rowp + 1 * HW_IN);
        const float4 f2 = *(const float4*)(rowp + 2 * HW_IN);
        const float4 f3 = *(const float4*)(rowp + 3 * HW_IN);
        const float4 f4 = *(const float4*)(rowp + 4 * HW_IN);
        const float4 f5 = *(const float4*)(rowp + 5 * HW_IN);
        const float4 f6 = *(const float4*)(rowp + 6 * HW_IN);
        const float4 f7 = *(const float4*)(rowp + 7 * HW_IN);

        // Per head H: for each output channel o, base = b0 + w1*x1 hoisted
        // out of the 4-column loop (saves ~96 VALU/thread vs folding).
#define L0_HEAD(P_, X0V, X1, M0A, M0B)                                          \
        {                                                                       \
            _Pragma("unroll")                                                   \
            for (int o = 0; o < 8; o++) {                                       \
                const float* w0r = P_ + OW0 + o * 10;                           \
                const float base = P_[OB0 + o] + w0r[1] * (X1);                 \
                const float w0  = w0r[0];                                       \
                const float wc0 = w0r[2], wc1 = w0r[3], wc2 = w0r[4],           \
                            wc3 = w0r[5], wc4 = w0r[6], wc5 = w0r[7],           \
                            wc6 = w0r[8], wc7 = w0r[9];                         \
                float a0 = base + w0 * X0V[0]                                   \
                         + wc0 * f0.x + wc1 * f1.x + wc2 * f2.x + wc3 * f3.x    \
                         + wc4 * f4.x + wc5 * f5.x + wc6 * f6.x + wc7 * f7.x;   \
                float a1 = base + w0 * X0V[1]                                   \
                         + wc0 * f0.y + wc1 * f1.y + wc2 * f2.y + wc3 * f3.y    \
                         + wc4 * f4.y + wc5 * f5.y + wc6 * f6.y + wc7 * f7.y;   \
                float a2 = base + w0 * X0V[2]                                   \
                         + wc0 * f0.z + wc1 * f1.z + wc2 * f2.z + wc3 * f3.z    \
                         + wc4 * f4.z + wc5 * f5.z + wc6 * f6.z + wc7 * f7.z;   \
                float a3 = base + w0 * X0V[3]                                   \
                         + wc0 * f0.w + wc1 * f1.w + wc2 * f2.w + wc3 * f3.w    \
                         + wc4 * f4.w + wc5 * f5.w + wc6 * f6.w + wc7 * f7.w;   \
                M0A[o] = fmaxf(M0A[o], fmaxf(a0, a1));                          \
                M0B[o] = fmaxf(M0B[o], fmaxf(a2, a3));                          \
            }                                                                   \
        }
        L0_HEAD(PA, x0A, x1A, m0aA, m0bA)
        L0_HEAD(PB, x0B, x1B, m0aB, m0bB)
#undef L0_HEAD
    }

    // ---- conv1 (relu) + pool over qx (local) and qy (cross-lane), per head -
#define L1_HEAD(P_, M0A, M0B, HID)                                              \
    {                                                                           \
        _Pragma("unroll")                                                       \
        for (int o = 0; o < 8; o++) {                                           \
            float a = P_[OB1 + o];                                              \
            float b = a;                                                        \
            _Pragma("unroll")                                                   \
            for (int c = 0; c < 8; c++) {                                       \
                const float w = P_[OW1 + o * 8 + c];                            \
                a += w * M0A[c];                                                \
                b += w * M0B[c];                                                \
            }                                                                   \
            const float h = fmaxf(fmaxf(a, b), 0.0f);                           \
            const float m = fmaxf(h, __shfl_xor(h, 32, 64));                    \
            if (qy == HID) s_m1[HID][pix][o] = m;  /* half HID stages head HID */\
        }                                                                       \
    }
    L1_HEAD(PA, m0aA, m0bA, 0)
    L1_HEAD(PB, m0aB, m0bB, 1)
#undef L1_HEAD
    __syncthreads();

    // ---- conv2 (relu): one output channel per thread, both heads ----------
    const int o = tid;                        // output channel 0..63
#define L2_HEAD(P_, HID)                                                        \
    {                                                                           \
        const float4 wa = *(const float4*)(P_ + OW2 + o * 8);                   \
        const float4 wb = *(const float4*)(P_ + OW2 + o * 8 + 4);               \
        const float  bo = P_[OB2 + o];                                          \
        float accum = 0.0f;                                                     \
        _Pragma("unroll 4")                                                     \
        for (int p2 = 0; p2 < CPIX; p2++) {                                     \
            const float4 va = *(const float4*)&s_m1[HID][p2][0];                \
            const float4 vb = *(const float4*)&s_m1[HID][p2][4];                \
            float a = bo + wa.x * va.x + wa.y * va.y + wa.z * va.z              \
                         + wa.w * va.w + wb.x * vb.x + wb.y * vb.y              \
                         + wb.z * vb.z + wb.w * vb.w;                           \
            accum += fmaxf(a, 0.0f);                                            \
        }                                                                       \
        ws_part[(((size_t)inst * 2 + HID) * NCHUNK + chunk) * 64 + o] = accum;  \
    }
    L2_HEAD(PA, 0)
    L2_HEAD(PB, 1)
#undef L2_HEAD
}

// ---------------------------------------------------------------------------
// K2: combine partials -> mean -> MLP (fc1 -> LN -> SELU -> fc2) -> logits
// ---------------------------------------------------------------------------
__global__ __launch_bounds__(128) void track_head_mlp(
    const float* __restrict__ ws_part,
    const float* __restrict__ mw1, const float* __restrict__ mb1,
    const float* __restrict__ mg,  const float* __restrict__ mbeta,
    const float* __restrict__ mw2, const float* __restrict__ mb2,
    const float* __restrict__ sw1, const float* __restrict__ sb1,
    const float* __restrict__ sg,  const float* __restrict__ sbeta,
    const float* __restrict__ sw2, const float* __restrict__ sb2,
    float*       __restrict__ out,
    int n_inst)
{
    const int inst = blockIdx.x;
    const int head = blockIdx.y;
    const int tid  = threadIdx.x;
    const int lane = tid & 63;
    const int wid  = tid >> 6;

    __shared__ __align__(16) float s_x[64];
    __shared__ __align__(16) float s_h[128];
    __shared__ float s_r[4];

    if (tid < 64) {
        const float* base = ws_part + ((size_t)inst * 2 + head) * NCHUNK * 64 + tid;
        float xm = 0.0f;
        #pragma unroll
        for (int q = 0; q < NCHUNK; q++) xm += base[q * 64];
        s_x[tid] = xm * (1.0f / (float)NPIX);
    }
    __syncthreads();

    const float* __restrict__ w1h = head ? sw1 : mw1;
    const float* __restrict__ b1h = head ? sb1 : mb1;
    const float* __restrict__ gh  = head ? sg  : mg;
    const float* __restrict__ bth = head ? sbeta : mbeta;
    const float* __restrict__ w2h = head ? sw2 : mw2;
    const float* __restrict__ b2h = head ? sb2 : mb2;

    float hval = 0.0f, dval = 0.0f;
    {
        const float* wr = w1h + tid * 64;
        float a = b1h[tid];
        #pragma unroll
        for (int k = 0; k < 16; k++) {
            const float4 wv = *(const float4*)(wr + k * 4);
            const float4 xv = *(const float4*)(&s_x[k * 4]);
            a += wv.x * xv.x + wv.y * xv.y + wv.z * xv.z + wv.w * xv.w;
        }
        hval = a;
    }
    {
        float s = hval;
        #pragma unroll
        for (int m = 32; m >= 1; m >>= 1) s += __shfl_xor(s, m, 64);
        if (lane == 0) s_r[wid] = s;
    }
    __syncthreads();
    const float mu = (s_r[0] + s_r[1]) * (1.0f / 128.0f);
    dval = hval - mu;
    {
        float s = dval * dval;
        #pragma unroll
        for (int m = 32; m >= 1; m >>= 1) s += __shfl_xor(s, m, 64);
        if (lane == 0) s_r[wid + 2] = s;
    }
    __syncthreads();
    const float var = (s_r[2] + s_r[3]) * (1.0f / 128.0f);

    {
        const float hn = dval * (1.0f / sqrtf(var + 1e-5f)) * gh[tid] + bth[tid];
        const float sv = (hn > 0.0f)
                           ? SELU_SCALE * hn
                           : SELU_SCALE * SELU_ALPHA * (expf(hn) - 1.0f);
        s_h[tid] = sv;
    }
    __syncthreads();

    if (tid < 64) {
        const float* wr = w2h + tid * 128;
        float a = b2h[tid];
        #pragma unroll
        for (int k = 0; k < 32; k++) {
            const float4 wv = *(const float4*)(wr + k * 4);
            const float4 hv = *(const float4*)(&s_h[k * 4]);
            a += wv.x * hv.x + wv.y * hv.y + wv.z * hv.z + wv.w * hv.w;
        }
        out[(size_t)head * (size_t)n_inst * 64 + (size_t)inst * 64 + tid] = a;
    }
}

extern "C" void kernel_launch(void* const* d_in, const int* in_sizes, int n_in,
                              void* d_out, int out_size, void* d_ws, size_t ws_size,
                              hipStream_t stream) {
    const float* mask_feats  = (const float*)d_in[0];
    const float* pmain       = (const float*)d_in[1];
    const float* pside       = (const float*)d_in[2];
    const int*   im_inds     = (const int*)  d_in[3];
    const float* inst_loc    = (const float*)d_in[4];
    const float* offset_pred = (const float*)d_in[5];
    const int*   fpn_levels  = (const int*)  d_in[6];
    const float* mw1   = (const float*)d_in[7];
    const float* mb1   = (const float*)d_in[8];
    const float* mg    = (const float*)d_in[9];
    const float* mbeta = (const float*)d_in[10];
    const float* mw2   = (const float*)d_in[11];
    const float* mb2   = (const float*)d_in[12];
    const float* sw1   = (const float*)d_in[13];
    const float* sb1   = (const float*)d_in[14];
    const float* sg    = (const float*)d_in[15];
    const float* sbeta = (const float*)d_in[16];
    const float* sw2   = (const float*)d_in[17];
    const float* sb2   = (const float*)d_in[18];
    const int*   strid = (const int*)  d_in[19];
    float* out = (float*)d_out;

    const int n_inst = in_sizes[3];   // im_inds length
    float* ws_part = (float*)d_ws;    // n_inst*2*NCHUNK*64 floats ~= 2 MB

    dim3 g1(n_inst, NCHUNK);
    track_head_conv<<<g1, 64, 0, stream>>>(
        mask_feats, pmain, pside, im_inds, inst_loc, offset_pred, fpn_levels,
        strid, ws_part);

    dim3 g2(n_inst, 2);
    track_head_mlp<<<g2, 128, 0, stream>>>(
        ws_part,
        mw1, mb1, mg, mbeta, mw2, mb2,
        sw1, sb1, sg, sbeta, sw2, sb2,
        out, n_inst);
}